// Round 11
// baseline (105.772 us; speedup 1.0000x reference)
//
#include <hip/hip_runtime.h>
#include <hip/hip_bf16.h>

#define SEQ  256
#define DIM  20
#define NCLS 5

typedef short  bf16x8 __attribute__((ext_vector_type(8)));
typedef float  f32x4  __attribute__((ext_vector_type(4)));
typedef float  v2f    __attribute__((ext_vector_type(2)));

__device__ __forceinline__ v2f fast_tanh2(v2f x) {
    // tanh(x) = 1 - 2/(exp(2x)+1); packed mul/add/fma, scalar exp/rcp
    v2f xs = x * 2.8853900817779268f;           // v_pk_mul_f32
    v2f e;
    e.x = __builtin_amdgcn_exp2f(xs.x);
    e.y = __builtin_amdgcn_exp2f(xs.y);
    v2f d = e + 1.0f;                           // v_pk_add_f32
    v2f r;
    r.x = __builtin_amdgcn_rcpf(d.x);
    r.y = __builtin_amdgcn_rcpf(d.y);
    return __builtin_elementwise_fma((v2f)(-2.0f), r, (v2f)(1.0f)); // v_pk_fma
}

__device__ __forceinline__ int cvt_pk_bf16(float lo, float hi) {
    int r;
    asm("v_cvt_pk_bf16_f32 %0, %1, %2" : "=v"(r) : "v"(lo), "v"(hi));
    return r;
}

// v_permlane32_swap_b32 a, b  (S1 semantics, established by r8/r9 A-B result):
//   a' : lanes 0-31 = a(0-31),  lanes 32-63 = b(0-31)
//   b' : lanes 0-31 = a(32-63), lanes 32-63 = b(32-63)
__device__ __forceinline__ void pl32swap(int &a, int &b) {
    asm("v_permlane32_swap_b32 %0, %1" : "+v"(a), "+v"(b));
}

// Recurrent-contraction column permutation (A-column kappa holds unit
// perm(kappa)): [0-3]->u0-3, [4-7]->u8-11, [8-11]->u4-7, [12-15]->u12-15,
// [16-19]->u16-19. Whole h-exchange = 2 permlane32_swap, zero DS.
__device__ __forceinline__ int permk(int k) {
    return (k >= 4 && k < 8) ? k + 4 : (k >= 8 && k < 12) ? k - 4 : k;
}

union I4B { int i[4]; bf16x8 f; };

// One RNN sub-step. BEC: current B-frag (consumed). BEN: next B-frag (written
// from the raw gather LOP/HIP_/NZP issued one sub-step earlier). Issues the
// gather for e(s+2) into LON/HIN/NZN and the token for s+3 (index I3).
#define RSTEP(BEC, BEN, LOP, HIP_, NZP, LON, HIN, NZN, I3)                     \
    {                                                                          \
        const float* _ep = emb + (size_t)tokN * DIM;                           \
        LON = *(const float4*)(_ep + eoff0);                                   \
        HIN = *(const float4*)(_ep + eoff1);                                   \
        NZN = (tokN != 0);                                                     \
        const int _tokNext = xp[(I3)];                                         \
        const f32x4 _ae0 = __builtin_amdgcn_mfma_f32_16x16x32_bf16(A0e, BEC.f, zf, 0, 0, 0); \
        const f32x4 _ae1 = __builtin_amdgcn_mfma_f32_16x16x32_bf16(A1e, BEC.f, zf, 0, 0, 0); \
        const f32x4 _ac0 = __builtin_amdgcn_mfma_f32_16x16x32_bf16(A0h, Bh.f, _ae0, 0, 0, 0); \
        const f32x4 _ac1 = __builtin_amdgcn_mfma_f32_16x16x32_bf16(A1h, Bh.f, _ae1, 0, 0, 0); \
        const v2f _p0 = fast_tanh2((v2f){_ac0[0], _ac0[1]});                   \
        const v2f _p1 = fast_tanh2((v2f){_ac0[2], _ac0[3]});                   \
        const v2f _p2 = fast_tanh2((v2f){_ac1[0], _ac1[1]});                   \
        const v2f _p3 = fast_tanh2((v2f){_ac1[2], _ac1[3]});                   \
        int _w0 = cvt_pk_bf16(_p0.x, _p0.y);                                   \
        int _w1 = cvt_pk_bf16(_p1.x, _p1.y);                                   \
        int _t0 = cvt_pk_bf16(_p2.x, _p2.y);                                   \
        int _t1 = cvt_pk_bf16(_p3.x, _p3.y);                                   \
        pl32swap(_w0, _t0);   /* w'={w_lo,t_lo}; t'={w_hi,t_hi} */             \
        pl32swap(_w1, _t1);                                                    \
        Bh.i[0] = _w0; Bh.i[1] = _w1; Bh.i[2] = _t0; Bh.i[3] = _t1;            \
        BEN.i[0] = NZP ? cvt_pk_bf16(LOP.x, LOP.y) : 0;                        \
        BEN.i[1] = NZP ? cvt_pk_bf16(LOP.z, LOP.w) : 0;                        \
        BEN.i[2] = NZP ? cvt_pk_bf16(HIP_.x, HIP_.y) : 0;                      \
        BEN.i[3] = NZP ? cvt_pk_bf16(HIP_.z, HIP_.w) : 0;                      \
        tokN = _tokNext;                                                       \
    }

// One wave = 8 batch rows (B-frag cols c and c+8 duplicate row c&7; only
// c<8 writes out). 2048 waves -> 2 waves/SIMD: partner wave hides each
// wave's dependency/memory stalls. Depth-2 e-prefetch, unroll-2 ping-pong.
__global__ __launch_bounds__(256, 2)
void rnn_mfma(const int* __restrict__ x,
              const float* __restrict__ emb,
              const float* __restrict__ W_ih,
              const float* __restrict__ W_hh,
              const float* __restrict__ W_cls,
              const float* __restrict__ b_cls,
              float* __restrict__ out, int B)
{
    const int gtid = blockIdx.x * blockDim.x + threadIdx.x;
    const int wave = gtid >> 6;
    const int lane = (int)(threadIdx.x & 63);
    const int c = lane & 15;      // B-frag column (c and c+8 carry row c&7)
    const int q = lane >> 4;      // quadrant
    const int row0 = wave * 8;
    if (row0 >= B) return;
    const int myrow = row0 + (c & 7);

    // ---- A fragments: lane holds A[row=c][k=8q+j], zero outside bounds.
    auto loadA = [&](const float* M, int U0, int ROWS, bool pk) {
        bf16x8 f;
        const int uu = U0 + c;
        const int ur = uu < ROWS ? uu : 0;           // clamped in-bounds addr
#pragma unroll
        for (int j = 0; j < 8; ++j) {
            const int kk = 8 * q + j;
            const int kp = pk ? permk(kk) : kk;      // recurrent k-permutation
            const int kr = kp < DIM ? kp : 0;
            float v = M[ur * DIM + kr];
            v = (uu < ROWS && kk < DIM) ? v : 0.0f;
            __hip_bfloat16 hb = __float2bfloat16(v);
            f[j] = *reinterpret_cast<short*>(&hb);
        }
        return f;
    };
    const bf16x8 A0h = loadA(W_hh,  0, DIM,  true);   // units 0-15,  W_hh
    const bf16x8 A0e = loadA(W_ih,  0, DIM,  false);  // units 0-15,  W_ih
    const bf16x8 A1h = loadA(W_hh, 16, DIM,  true);   // units 16-19
    const bf16x8 A1e = loadA(W_ih, 16, DIM,  false);
    const bf16x8 Acl = loadA(W_cls, 0, NCLS, true);   // classes 0-4

    float bias[4];
#pragma unroll
    for (int j = 0; j < 4; ++j) {
        const int idx = 4 * q + j;
        bias[j] = (idx < NCLS) ? b_cls[idx] : 0.0f;
    }

    const int eoff0 = (q == 0) ? 0 : (q == 1) ? 8 : 16;   // e element offsets,
    const int eoff1 = (q == 0) ? 4 : (q == 1) ? 12 : 16;  // clamped in-bounds

    const int* xp = x + (size_t)myrow * SEQ;
    const f32x4 zf = {0.0f, 0.0f, 0.0f, 0.0f};

    // ---- prologue: Be0 = e(0) converted; e(1) raw in flight; tokN = t(2).
    I4B Bh; Bh.i[0] = Bh.i[1] = Bh.i[2] = Bh.i[3] = 0;
    I4B Be0, Be1;
    const int tok0 = xp[0];
    const int tok1 = xp[1];
    int tokN = xp[2];
    {
        const float* ep = emb + (size_t)tok0 * DIM;
        float4 lo = *(const float4*)(ep + eoff0);
        float4 hi = *(const float4*)(ep + eoff1);
        const bool nz = (tok0 != 0);  // padding_idx = 0
        Be0.i[0] = nz ? cvt_pk_bf16(lo.x, lo.y) : 0;
        Be0.i[1] = nz ? cvt_pk_bf16(lo.z, lo.w) : 0;
        Be0.i[2] = nz ? cvt_pk_bf16(hi.x, hi.y) : 0;
        Be0.i[3] = nz ? cvt_pk_bf16(hi.z, hi.w) : 0;
    }
    float4 loA, hiA, loB, hiB;
    bool nzA, nzB;
    {
        const float* ep = emb + (size_t)tok1 * DIM;
        loA = *(const float4*)(ep + eoff0);
        hiA = *(const float4*)(ep + eoff1);
        nzA = (tok1 != 0);
    }

    // main loop: sub-steps 0..251, no clamps (max token index = 251+3 = 254)
#pragma unroll 1
    for (int s = 0; s < 252; s += 2) {
        RSTEP(Be0, Be1, loA, hiA, nzA, loB, hiB, nzB, s + 3)
        RSTEP(Be1, Be0, loB, hiB, nzB, loA, hiA, nzA, s + 4)
    }
    // peeled tail: sub-steps 252..255 (token index clamped to 255)
    RSTEP(Be0, Be1, loA, hiA, nzA, loB, hiB, nzB, 255)
    RSTEP(Be1, Be0, loB, hiB, nzB, loA, hiA, nzA, 255)
    RSTEP(Be0, Be1, loA, hiA, nzA, loB, hiB, nzB, 255)
    RSTEP(Be1, Be0, loB, hiB, nzB, loA, hiA, nzA, 255)

    // ---- classifier: one MFMA (classes in rows 0-4; k-cols >= 20 are zero)
    const f32x4 y = __builtin_amdgcn_mfma_f32_16x16x32_bf16(Acl, Bh.f, zf, 0, 0, 0);
    if (c < 8) {
        float* orow = out + (size_t)myrow * NCLS;
        if (q == 0) {          // rows 0-3 = classes 0-3 for batch row c
            orow[0] = y[0] + bias[0];
            orow[1] = y[1] + bias[1];
            orow[2] = y[2] + bias[2];
            orow[3] = y[3] + bias[3];
        } else if (q == 1) {   // row 4 = class 4
            orow[4] = y[0] + bias[0];
        }
    }
}

extern "C" void kernel_launch(void* const* d_in, const int* in_sizes, int n_in,
                              void* d_out, int out_size, void* d_ws, size_t ws_size,
                              hipStream_t stream) {
    const int*   x     = (const int*)d_in[0];
    const float* emb   = (const float*)d_in[1];
    const float* W_ih  = (const float*)d_in[2];
    const float* W_hh  = (const float*)d_in[3];
    const float* W_cls = (const float*)d_in[4];
    const float* b_cls = (const float*)d_in[5];
    float* out = (float*)d_out;

    const int B = in_sizes[0] / SEQ;            // 16384
    const int threads = B * 8;                   // 64 lanes per 8 rows
    const int block = 256;
    const int grid = (threads + block - 1) / block;   // 2048 waves total
    rnn_mfma<<<grid, block, 0, stream>>>(x, emb, W_ih, W_hh, W_cls, b_cls, out, B);
}

// Round 12
// 91.643 us; speedup vs baseline: 1.1542x; 1.1542x over previous
//
#include <hip/hip_runtime.h>
#include <hip/hip_bf16.h>

#define SEQ  256
#define DIM  20
#define NCLS 5

typedef short  bf16x8 __attribute__((ext_vector_type(8)));
typedef float  f32x4  __attribute__((ext_vector_type(4)));
typedef float  v2f    __attribute__((ext_vector_type(2)));

__device__ __forceinline__ v2f fast_tanh2(v2f x) {
    // tanh(x) = 1 - 2/(exp(2x)+1); packed mul/add/fma, scalar exp/rcp
    v2f xs = x * 2.8853900817779268f;           // v_pk_mul_f32
    v2f e;
    e.x = __builtin_amdgcn_exp2f(xs.x);
    e.y = __builtin_amdgcn_exp2f(xs.y);
    v2f d = e + 1.0f;                           // v_pk_add_f32
    v2f r;
    r.x = __builtin_amdgcn_rcpf(d.x);
    r.y = __builtin_amdgcn_rcpf(d.y);
    return __builtin_elementwise_fma((v2f)(-2.0f), r, (v2f)(1.0f)); // v_pk_fma
}

__device__ __forceinline__ int cvt_pk_bf16(float lo, float hi) {
    int r;
    asm("v_cvt_pk_bf16_f32 %0, %1, %2" : "=v"(r) : "v"(lo), "v"(hi));
    return r;
}

// v_permlane32_swap_b32 a, b  (S1 semantics, established by r8/r9 A-B result):
//   a' : lanes 0-31 = a(0-31),  lanes 32-63 = b(0-31)
//   b' : lanes 0-31 = a(32-63), lanes 32-63 = b(32-63)
__device__ __forceinline__ void pl32swap(int &a, int &b) {
    asm("v_permlane32_swap_b32 %0, %1" : "+v"(a), "+v"(b));
}

// Recurrent-contraction column permutation (A-column kappa holds unit
// perm(kappa)): [0-3]->u0-3, [4-7]->u8-11, [8-11]->u4-7, [12-15]->u12-15,
// [16-19]->u16-19. Whole h-exchange = 2 permlane32_swap, zero DS.
__device__ __forceinline__ int permk(int k) {
    return (k >= 4 && k < 8) ? k + 4 : (k >= 8 && k < 12) ? k - 4 : k;
}

union I4B { int i[4]; bf16x8 f; };

// One wave = 16 batch rows. Steady-state chain per step = ONE h-MFMA + tanh
// + cvt + swap: the e-MFMAs for step s+1 are issued at the BOTTOM of step s
// (right after Be(s+1) is converted), so their latency is covered by a full
// iteration and they enter the h-MFMA as a ready C operand.
// DEPTH-3 e-prefetch: gather for e(s+3) issued at iter s; the convert of
// e(s+1) waits on loads ~2.5 steps old (beyond worst-case HBM latency).
__global__ __launch_bounds__(256, 1)
void rnn_mfma(const int* __restrict__ x,
              const float* __restrict__ emb,
              const float* __restrict__ W_ih,
              const float* __restrict__ W_hh,
              const float* __restrict__ W_cls,
              const float* __restrict__ b_cls,
              float* __restrict__ out, int B)
{
    const int gtid = blockIdx.x * blockDim.x + threadIdx.x;
    const int wave = gtid >> 6;
    const int lane = (int)(threadIdx.x & 63);
    const int c = lane & 15;      // batch column of the tile
    const int q = lane >> 4;      // quadrant
    const int row0 = wave * 16;
    if (row0 >= B) return;

    // ---- A fragments: lane holds A[row=c][k=8q+j], zero outside bounds.
    auto loadA = [&](const float* M, int U0, int ROWS, bool pk) {
        bf16x8 f;
        const int uu = U0 + c;
        const int ur = uu < ROWS ? uu : 0;           // clamped in-bounds addr
#pragma unroll
        for (int j = 0; j < 8; ++j) {
            const int kk = 8 * q + j;
            const int kp = pk ? permk(kk) : kk;      // recurrent k-permutation
            const int kr = kp < DIM ? kp : 0;
            float v = M[ur * DIM + kr];
            v = (uu < ROWS && kk < DIM) ? v : 0.0f;
            __hip_bfloat16 hb = __float2bfloat16(v);
            f[j] = *reinterpret_cast<short*>(&hb);
        }
        return f;
    };
    const bf16x8 A0h = loadA(W_hh,  0, DIM,  true);   // units 0-15,  W_hh
    const bf16x8 A0e = loadA(W_ih,  0, DIM,  false);  // units 0-15,  W_ih
    const bf16x8 A1h = loadA(W_hh, 16, DIM,  true);   // units 16-19
    const bf16x8 A1e = loadA(W_ih, 16, DIM,  false);
    const bf16x8 Acl = loadA(W_cls, 0, NCLS, true);   // classes 0-4

    float bias[4];
#pragma unroll
    for (int j = 0; j < 4; ++j) {
        const int idx = 4 * q + j;
        bias[j] = (idx < NCLS) ? b_cls[idx] : 0.0f;
    }

    const int eoff0 = (q == 0) ? 0 : (q == 1) ? 8 : 16;   // e element offsets,
    const int eoff1 = (q == 0) ? 4 : (q == 1) ? 12 : 16;  // clamped in-bounds

    const int* xp = x + (size_t)(row0 + c) * SEQ;
    const f32x4 zf = {0.0f, 0.0f, 0.0f, 0.0f};

    // ---- prologue ------------------------------------------------------
    I4B Bh; Bh.i[0] = Bh.i[1] = Bh.i[2] = Bh.i[3] = 0;
    I4B Be;
    const int t0 = xp[0];
    const int t1 = xp[1];
    const int t2 = xp[2];
    int tokG = xp[3];                 // token for the gather issued at iter s (e(s+3))

    {   // e(0): gather + convert now; aePre for step 0
        const float* ep = emb + (size_t)t0 * DIM;
        float4 lo = *(const float4*)(ep + eoff0);
        float4 hi = *(const float4*)(ep + eoff1);
        const bool nz = (t0 != 0);    // padding_idx = 0
        Be.i[0] = nz ? cvt_pk_bf16(lo.x, lo.y) : 0;
        Be.i[1] = nz ? cvt_pk_bf16(lo.z, lo.w) : 0;
        Be.i[2] = nz ? cvt_pk_bf16(hi.x, hi.y) : 0;
        Be.i[3] = nz ? cvt_pk_bf16(hi.z, hi.w) : 0;
    }
    f32x4 aePre0 = __builtin_amdgcn_mfma_f32_16x16x32_bf16(A0e, Be.f, zf, 0, 0, 0);
    f32x4 aePre1 = __builtin_amdgcn_mfma_f32_16x16x32_bf16(A1e, Be.f, zf, 0, 0, 0);

    // raw stages: A = e(s+1), B = e(s+2)
    float4 loA, hiA, loB, hiB;
    bool nzA, nzB;
    {
        const float* ep = emb + (size_t)t1 * DIM;
        loA = *(const float4*)(ep + eoff0);
        hiA = *(const float4*)(ep + eoff1);
        nzA = (t1 != 0);
    }
    {
        const float* ep = emb + (size_t)t2 * DIM;
        loB = *(const float4*)(ep + eoff0);
        hiB = *(const float4*)(ep + eoff1);
        nzB = (t2 != 0);
    }

    // ---- main loop ------------------------------------------------------
#pragma unroll 2
    for (int s = 0; s < SEQ; ++s) {
        // issue gather e(s+3) + token(s+4) — consumed 3 / 1 iterations later
        const float* ep = emb + (size_t)tokG * DIM;
        const float4 loC = *(const float4*)(ep + eoff0);
        const float4 hiC = *(const float4*)(ep + eoff1);
        const bool nzC = (tokG != 0);
        const int i4 = (s + 4 < SEQ) ? s + 4 : SEQ - 1;
        const int tokGn = xp[i4];

        // steady-state chain: ONE MFMA (aePre is a ready C operand)
        const f32x4 acc0 = __builtin_amdgcn_mfma_f32_16x16x32_bf16(A0h, Bh.f, aePre0, 0, 0, 0);
        const f32x4 acc1 = __builtin_amdgcn_mfma_f32_16x16x32_bf16(A1h, Bh.f, aePre1, 0, 0, 0);

        // tanh (packed), pack to bf16, exchange (2 VALU cross-lane swaps)
        const v2f p0 = fast_tanh2((v2f){acc0[0], acc0[1]});
        const v2f p1 = fast_tanh2((v2f){acc0[2], acc0[3]});
        const v2f p2 = fast_tanh2((v2f){acc1[0], acc1[1]});
        const v2f p3 = fast_tanh2((v2f){acc1[2], acc1[3]});
        int w0  = cvt_pk_bf16(p0.x, p0.y);
        int w1  = cvt_pk_bf16(p1.x, p1.y);
        int tp0 = cvt_pk_bf16(p2.x, p2.y);
        int tp1 = cvt_pk_bf16(p3.x, p3.y);
        pl32swap(w0, tp0);   // w' = {w_low, t_low}; t' = {w_high, t_high}
        pl32swap(w1, tp1);
        Bh.i[0] = w0;
        Bh.i[1] = w1;
        Bh.i[2] = tp0;
        Bh.i[3] = tp1;

        // convert e(s+1): loads ~2.5 iterations old -> vmcnt wait is covered
        Be.i[0] = nzA ? cvt_pk_bf16(loA.x, loA.y) : 0;
        Be.i[1] = nzA ? cvt_pk_bf16(loA.z, loA.w) : 0;
        Be.i[2] = nzA ? cvt_pk_bf16(hiA.x, hiA.y) : 0;
        Be.i[3] = nzA ? cvt_pk_bf16(hiA.z, hiA.w) : 0;

        // e-MFMAs for step s+1 issued HERE: a full iteration of latency cover
        aePre0 = __builtin_amdgcn_mfma_f32_16x16x32_bf16(A0e, Be.f, zf, 0, 0, 0);
        aePre1 = __builtin_amdgcn_mfma_f32_16x16x32_bf16(A1e, Be.f, zf, 0, 0, 0);

        // rotate raw stages (renamed away by the unroll)
        loA = loB; hiA = hiB; nzA = nzB;
        loB = loC; hiB = hiC; nzB = nzC;
        tokG = tokGn;
    }

    // ---- classifier: one MFMA (classes in rows 0-4; k-cols >= 20 are zero)
    const f32x4 y = __builtin_amdgcn_mfma_f32_16x16x32_bf16(Acl, Bh.f, zf, 0, 0, 0);
    float* orow = out + (size_t)(row0 + c) * NCLS;
    if (q == 0) {          // rows 0-3 = classes 0-3 for batch row c
        orow[0] = y[0] + bias[0];
        orow[1] = y[1] + bias[1];
        orow[2] = y[2] + bias[2];
        orow[3] = y[3] + bias[3];
    } else if (q == 1) {   // row 4 = class 4
        orow[4] = y[0] + bias[0];
    }
}

extern "C" void kernel_launch(void* const* d_in, const int* in_sizes, int n_in,
                              void* d_out, int out_size, void* d_ws, size_t ws_size,
                              hipStream_t stream) {
    const int*   x     = (const int*)d_in[0];
    const float* emb   = (const float*)d_in[1];
    const float* W_ih  = (const float*)d_in[2];
    const float* W_hh  = (const float*)d_in[3];
    const float* W_cls = (const float*)d_in[4];
    const float* b_cls = (const float*)d_in[5];
    float* out = (float*)d_out;

    const int B = in_sizes[0] / SEQ;            // 16384
    const int threads = B * 4;                   // 64 lanes per 16 rows
    const int block = 256;
    const int grid = (threads + block - 1) / block;   // 1024 waves total
    rnn_mfma<<<grid, block, 0, stream>>>(x, emb, W_ih, W_hh, W_cls, b_cls, out, B);
}